// Round 19
// baseline (24.824 us; speedup 1.0000x reference)
//
#include <hip/hip_runtime.h>

typedef float f4 __attribute__((ext_vector_type(4)));
typedef float f2 __attribute__((ext_vector_type(2)));
typedef f2 __attribute__((aligned(4))) f2u;   // 4B-aligned pair -> ds_write2_b32

#define NJ 24
#define BLK 128
#define OUTW 75               // (NJ+1)*3 floats per row
#define HROWS 32              // rows staged per dump phase (half wave)
#define HBUF (HROWS * OUTW)   // 2400 floats = 9.6 KB per wave

// broadcast lane j's float to all lanes as wave-uniform SGPR (no DS pipe)
#define RL(v, j) __int_as_float(__builtin_amdgcn_readlane(__float_as_int(v), (j)))

__global__ __launch_bounds__(BLK, 4) void fk_main_kernel(
    const float* __restrict__ ang,   // (B, 24)
    const float* __restrict__ xyz,   // (24, 3)
    const float* __restrict__ rpy,   // (24, 3)
    const float* __restrict__ axis,  // (24, 3)
    float* __restrict__ out)         // (B, 75)
{
    // LDS is ONLY the per-wave staging bounce: 2 x 9.6 KB = 19200 B/block
    __shared__ float buf[(BLK / 64) * HBUF];

    const int tid = threadIdx.x;
    const int wv = tid >> 6, ln = tid & 63;
    float* wbuf = &buf[wv * HBUF];

    // ---- my row's 24 angles via 6x float4 (row base 96B -> 16B aligned) ----
    const long long row = (long long)blockIdx.x * BLK + tid;
    const f4* gA = (const f4*)(ang + row * NJ);
    f4 A[6];
    #pragma unroll
    for (int k = 0; k < 6; ++k) A[k] = gA[k];

    // ---- per-joint consts: lanes 0..23 of EACH wave hold joint ln's 12 ----
    float c0=0,c1=0,c2=0,c3=0,c4=0,c5=0,c6=0,c7=0,c8=0,c9=0,c10=0,c11=0;
    if (ln < NJ) {
        const int j = ln;
        float r = rpy[j*3+0] * 0.5f, p = rpy[j*3+1] * 0.5f, yv = rpy[j*3+2] * 0.5f;
        float sr, cr, sp, cp, sy, cy;
        __sincosf(r, &sr, &cr);
        __sincosf(p, &sp, &cp);
        __sincosf(yv, &sy, &cy);
        float qw = cr*cp*cy + sr*sp*sy;
        float qx = sr*cp*cy - cr*sp*sy;
        float qy = cr*sp*cy + sr*cp*sy;
        float qz = cr*cp*sy - sr*sp*cy;
        float ax = axis[j*3+0], ay = axis[j*3+1], az = axis[j*3+2];
        float n = sqrtf(ax*ax + ay*ay + az*az);
        float inv = 1.0f / fmaxf(n, 1e-6f);
        float ux = ax*inv, uy = ay*inv, uz = az*inv;
        c0 = qw; c1 = qx; c2 = qy; c3 = qz;            // qA = qRo
        c4 = -(qx*ux + qy*uy + qz*uz);                  // qB = qRo x (0,u)
        c5 = qw*ux + qy*uz - qz*uy;
        c6 = qw*uy + qz*ux - qx*uz;
        c7 = qw*uz + qx*uy - qy*ux;
        c8 = xyz[j*3+0]; c9 = xyz[j*3+1]; c10 = xyz[j*3+2];
        c11 = n * 0.5f;
    }

    // ---- single FK chain; consts via readlane; math in f2 pairs so the
    //      backend emits v_pk_{mul,fma}_f32 (VOP3P, 2 FMA/slot, neg mods) ----
    float o[OUTW];                       // all indices compile-time -> VGPRs
    o[0] = 0.f; o[1] = 0.f; o[2] = 0.f;
    float Qw = 1.f, Qx = 0.f, Qy = 0.f, Qz = 0.f;
    f2 T01 = {0.f, 0.f};                 // (t0, t1)
    float t2 = 0.f;

    #pragma unroll
    for (int j = 0; j < NJ; ++j) {
        float qa0 = RL(c0, j), qa1 = RL(c1, j), qa2 = RL(c2, j), qa3 = RL(c3, j);
        float qb0 = RL(c4, j), qb1 = RL(c5, j), qb2 = RL(c6, j), qb3 = RL(c7, j);
        float vx  = RL(c8, j), vy  = RL(c9, j), vz  = RL(c10, j);
        float hn  = RL(c11, j);

        float h = A[j >> 2][j & 3] * hn;
        float s, cq;
        __sincosf(h, &s, &cq);

        // local quat: 2 pk_mul + 2 pk_fma
        f2 Lwx = cq * f2{qa0, qa1} + s * f2{qb0, qb1};
        f2 Lyz = cq * f2{qa2, qa3} + s * f2{qb2, qb3};
        float lw = Lwx.x, lx = Lwx.y, ly = Lyz.x, lz = Lyz.y;

        // rotate v by parent Q, accumulate t (pairs + scalar lane)
        f2 Qyz = {Qy, Qz}, Qzx = {Qz, Qx};
        f2 u01 = Qyz * f2{vz, vx} - Qzx * f2{vy, vz} + Qw * f2{vx, vy};
        float u2 = Qx*vy - Qy*vx + Qw*vz;
        f2 w01 = Qyz * f2{u2, u01.x} - Qzx * f2{u01.y, u2};
        float w2 = Qx*u01.y - Qy*u01.x;
        T01 = T01 + f2{vx, vy} + 2.f * w01;
        t2  = t2 + vz + 2.f * w2;
        o[3*(j+1)+0] = T01.x;
        o[3*(j+1)+1] = T01.y;
        o[3*(j+1)+2] = t2;

        // Q = Q (x) q_loc : 2x (pk_mul + 3 pk_fma), negs fold into VOP3P mods
        f2 Nwx = Qw * Lwx + Qx * f2{-lx, lw} + Qy * f2{-ly, lz} + Qz * f2{-lz, -ly};
        f2 Nyz = Qw * Lyz + Qx * f2{-lz, ly} + Qy * f2{lw, -lx} + Qz * f2{lx, lw};
        Qw = Nwx.x; Qx = Nwx.y; Qy = Nyz.x; Qz = Nyz.y;
    }

    // global f4 base for this wave's 64 rows (64*75*4 = 19200 B contiguous)
    f4* gW = (f4*)(out + ((long long)blockIdx.x * BLK + wv * 64) * OUTW);

    // ---- phase 0: lanes 0..31 stage full rows as f2 pairs (ds_write2_b32:
    // 2 dwords/issue at dword alignment -> 38 issues vs 75). Banks: pair k
    // starts at (11*ln + 2k) mod 32, bijective in ln -> conflict-free.
    // LDS ptrs deliberately NOT restrict (they alias; R6 lesson).
    if (ln < HROWS) {
        float* ob = wbuf + ln * OUTW;
        #pragma unroll
        for (int k = 0; k < 37; ++k)
            *(f2u*)(ob + 2*k) = f2{o[2*k], o[2*k+1]};
        ob[74] = o[74];
    }
    asm volatile("" ::: "memory");   // stage-writes -> dump-reads (RAW order)
    {
        const f4* lb = (const f4*)wbuf;          // 600 f4, contiguous
        #pragma unroll
        for (int k = 0; k < 10; ++k) {
            int i = k * 64 + ln;
            if (i < HBUF / 4) gW[i] = lb[i];
        }
    }
    asm volatile("" ::: "memory");   // dump-reads -> phase-1 stage-writes (WAR)

    // ---- phase 1: lanes 32..63 stage; whole wave dumps second 9.6 KB ----
    if (ln >= HROWS) {
        float* ob = wbuf + (ln - HROWS) * OUTW;
        #pragma unroll
        for (int k = 0; k < 37; ++k)
            *(f2u*)(ob + 2*k) = f2{o[2*k], o[2*k+1]};
        ob[74] = o[74];
    }
    asm volatile("" ::: "memory");   // stage-writes -> dump-reads (RAW order)
    {
        const f4* lb = (const f4*)wbuf;
        #pragma unroll
        for (int k = 0; k < 10; ++k) {
            int i = k * 64 + ln;
            if (i < HBUF / 4) gW[i + HBUF / 4] = lb[i];
        }
    }
}

extern "C" void kernel_launch(void* const* d_in, const int* in_sizes, int n_in,
                              void* d_out, int out_size, void* d_ws, size_t ws_size,
                              hipStream_t stream) {
    const float* ang  = (const float*)d_in[0];
    const float* xyz  = (const float*)d_in[1];
    const float* rpy  = (const float*)d_in[2];
    const float* axis = (const float*)d_in[3];
    float* out = (float*)d_out;

    const int B = in_sizes[0] / NJ;          // 262144
    const int grid = B / BLK;                // 2048 = 8 blocks/CU, one round
    fk_main_kernel<<<grid, BLK, 0, stream>>>(ang, xyz, rpy, axis, out);
}